// Round 5
// baseline (302.046 us; speedup 1.0000x reference)
//
#include <hip/hip_runtime.h>
#include <hip/hip_bf16.h>

// attention_84464826843938: additive-attention pooling, MI355X (gfx950)
//
// R5: barrier-free score GEMM.
//  R4 postmortem: any __syncthreads per K-step forces vmcnt(0) drain of
//  just-issued loads -> ~7500 cyc/step convoy regardless of prefetch order.
//  Fix: no LDS, no barriers in the K-loop. A-fragments gathered directly from
//  fp32 features in MFMA fragment order (32B/lane, 4 g-groups cover full 128B
//  lines), cvt to bf16 in-register; B-frags from pre-packed wpack (16B/lane).
//  Explicit 1-deep register pipeline; latency hidden by ILP + 4 waves/SIMD.
//  grid = 4 slices x 256 b (slice-major -> all slices of b on one XCD).

#define B_ 256
#define R_ 64
#define F_ 2048
#define H_ 512
#define DIM_ 512

typedef short bf16x8 __attribute__((ext_vector_type(8)));
typedef float f32x4 __attribute__((ext_vector_type(4)));

__device__ __forceinline__ ushort f2bf(float x) {
  __hip_bfloat16 h = __float2bfloat16(x);
  return __builtin_bit_cast(ushort, h);
}

__device__ __forceinline__ uint4 pack8(float4 x, float4 y) {
  uint4 r;
  r.x = (uint)f2bf(x.x) | ((uint)f2bf(x.y) << 16);
  r.y = (uint)f2bf(x.z) | ((uint)f2bf(x.w) << 16);
  r.z = (uint)f2bf(y.x) | ((uint)f2bf(y.y) << 16);
  r.w = (uint)f2bf(y.z) | ((uint)f2bf(y.w) << 16);
  return r;
}

// wpack[((kt32*32 + ctg)*64 + l)*8 + i] = bf16(W_w[kt32*32 + (l>>4)*8 + i][ctg*16 + (l&15)])
__global__ void pack_w_k(const float* __restrict__ Ww, ushort* __restrict__ wpack) {
  int idx = blockIdx.x * 256 + threadIdx.x;
  float v = Ww[idx];
  int k = idx >> 9;
  int d = idx & 511;
  int kt = k >> 5, kr = k & 31;
  int g = kr >> 3, i = kr & 7;
  int ctg = d >> 4, c = d & 15;
  size_t dst = ((size_t)((kt * 32 + ctg) * 64 + g * 16 + c)) * 8 + (size_t)i;
  wpack[dst] = f2bf(v);
}

// p'[b][d] = prev[b]@W2_w[:,d] + W2_b[d] + W_b[d]
__global__ __launch_bounds__(256) void prep_p_k(const float* __restrict__ prev,
                                                const float* __restrict__ W2w,
                                                const float* __restrict__ W2b,
                                                const float* __restrict__ Wb,
                                                float* __restrict__ pprime) {
  __shared__ float lprev[8][H_];
  int bg = blockIdx.x >> 3;
  int d0 = (blockIdx.x & 7) * 64;
  int t = threadIdx.x;
  const float4* src = reinterpret_cast<const float4*>(prev + (size_t)bg * 8 * H_);
  float4* dst = reinterpret_cast<float4*>(&lprev[0][0]);
  for (int i = t; i < 8 * H_ / 4; i += 256) dst[i] = src[i];
  __syncthreads();
  int d = d0 + (t & 63);
  int bq = t >> 6;
  float a0 = 0.f, a1 = 0.f;
  #pragma unroll 8
  for (int h = 0; h < H_; ++h) {
    float wv = W2w[h * DIM_ + d];
    a0 += lprev[bq][h] * wv;
    a1 += lprev[bq + 4][h] * wv;
  }
  float bias = W2b[d] + Wb[d];
  pprime[(size_t)(bg * 8 + bq) * DIM_ + d] = a0 + bias;
  pprime[(size_t)(bg * 8 + bq + 4) * DIM_ + d] = a1 + bias;
}

__device__ __forceinline__ float fast_tanh(float x) {
  float e = __expf(2.f * x);
  return 1.f - 2.f / (e + 1.f);
}

// sp[b*4+slice][r] = sum_{d in slice's 128 cols} tanh(c[b][r][d]+p'[b][d])*W3[d]
__global__ __launch_bounds__(256, 4) void score_k(const float* __restrict__ feat,
                                                  const ushort* __restrict__ wpack,
                                                  const float* __restrict__ pprime,
                                                  const float* __restrict__ W3,
                                                  float* __restrict__ sp) {
  int slice = blockIdx.x >> 8;          // slice-major: all slices of b same XCD
  int b = blockIdx.x & 255;
  int t = threadIdx.x;
  int wid = t >> 6;                     // 4 waves; wave owns cols [wid*32,+32)
  int l = t & 63;
  int l15 = l & 15, g = l >> 4;
  const float* fb = feat + (size_t)b * R_ * F_;

  __shared__ float lds_part[4][R_];

  // per-lane A row pointers: lane reads A[rt*16+l15][kt*32 + g*8 .. +8]
  const float* ap[4];
  #pragma unroll
  for (int rt = 0; rt < 4; ++rt)
    ap[rt] = fb + (size_t)(rt * 16 + l15) * F_ + g * 8;

  // per-lane B pointer: frag(kt,ct) at wp + kt*16384 + ct*512 (ushort units)
  const ushort* wp = wpack + (size_t)(slice * 8 + wid * 2) * 512 + (size_t)l * 8;

  f32x4 acc[4][2];
  #pragma unroll
  for (int rt = 0; rt < 4; ++rt)
    #pragma unroll
    for (int ct = 0; ct < 2; ++ct)
      acc[rt][ct] = (f32x4){0.f, 0.f, 0.f, 0.f};

  // prologue: load + cvt step 0
  bf16x8 af[4];
  uint4 bv0, bv1;
  {
    float4 x0[4], x1[4];
    #pragma unroll
    for (int rt = 0; rt < 4; ++rt) {
      const float4* p = reinterpret_cast<const float4*>(ap[rt]);
      x0[rt] = p[0];
      x1[rt] = p[1];
    }
    bv0 = *reinterpret_cast<const uint4*>(wp);
    bv1 = *reinterpret_cast<const uint4*>(wp + 512);
    #pragma unroll
    for (int rt = 0; rt < 4; ++rt)
      af[rt] = __builtin_bit_cast(bf16x8, pack8(x0[rt], x1[rt]));
  }

  for (int kt = 0; kt < 64; ++kt) {     // K-step = 32, no barriers
    float4 n0[4], n1[4];
    uint4 nb0, nb1;
    if (kt < 63) {
      #pragma unroll
      for (int rt = 0; rt < 4; ++rt) {
        const float4* p = reinterpret_cast<const float4*>(ap[rt] + (kt + 1) * 32);
        n0[rt] = p[0];
        n1[rt] = p[1];
      }
      const ushort* wb = wp + (size_t)(kt + 1) * 16384;
      nb0 = *reinterpret_cast<const uint4*>(wb);
      nb1 = *reinterpret_cast<const uint4*>(wb + 512);
    }

    bf16x8 bb0 = __builtin_bit_cast(bf16x8, bv0);
    bf16x8 bb1 = __builtin_bit_cast(bf16x8, bv1);
    #pragma unroll
    for (int rt = 0; rt < 4; ++rt)
      acc[rt][0] = __builtin_amdgcn_mfma_f32_16x16x32_bf16(af[rt], bb0, acc[rt][0], 0, 0, 0);
    #pragma unroll
    for (int rt = 0; rt < 4; ++rt)
      acc[rt][1] = __builtin_amdgcn_mfma_f32_16x16x32_bf16(af[rt], bb1, acc[rt][1], 0, 0, 0);

    if (kt < 63) {
      #pragma unroll
      for (int rt = 0; rt < 4; ++rt)
        af[rt] = __builtin_bit_cast(bf16x8, pack8(n0[rt], n1[rt]));
      bv0 = nb0;
      bv1 = nb1;
    }
  }

  // epilogue: tanh + W3 dot in registers
  // acc[rt][ct][j] = c[row = rt*16 + g*4 + j][col = slice*128 + wid*32 + ct*16 + l15]
  float pp[2], w3v[2];
  #pragma unroll
  for (int ct = 0; ct < 2; ++ct) {
    int col = slice * 128 + wid * 32 + ct * 16 + l15;
    pp[ct] = pprime[b * DIM_ + col];
    w3v[ct] = W3[col];
  }
  #pragma unroll
  for (int rt = 0; rt < 4; ++rt) {
    #pragma unroll
    for (int j = 0; j < 4; ++j) {
      float v = fast_tanh(acc[rt][0][j] + pp[0]) * w3v[0]
              + fast_tanh(acc[rt][1][j] + pp[1]) * w3v[1];
      v += __shfl_xor(v, 1);
      v += __shfl_xor(v, 2);
      v += __shfl_xor(v, 4);
      v += __shfl_xor(v, 8);
      if (l15 == 0) lds_part[wid][rt * 16 + g * 4 + j] = v;
    }
  }
  __syncthreads();

  if (t < R_) {
    float s = lds_part[0][t] + lds_part[1][t] + lds_part[2][t] + lds_part[3][t];
    sp[((size_t)b * 4 + slice) * R_ + t] = s;
  }
}

// softmax + weighted sum: grid = B*4, 256 thr, 512 f per block
__global__ __launch_bounds__(256) void wsum_k(const float* __restrict__ feat,
                                              const float* __restrict__ sp,
                                              float* __restrict__ out) {
  int b = blockIdx.x >> 2;
  int f0 = (blockIdx.x & 3) * 512;
  int t = threadIdx.x;
  __shared__ float lds_aw[R_];

  if (t < R_) {
    float s = sp[((size_t)b * 4 + 0) * R_ + t] + sp[((size_t)b * 4 + 1) * R_ + t]
            + sp[((size_t)b * 4 + 2) * R_ + t] + sp[((size_t)b * 4 + 3) * R_ + t];
    float m = s;
    #pragma unroll
    for (int off = 32; off >= 1; off >>= 1) m = fmaxf(m, __shfl_xor(m, off));
    float e = __expf(s - m);
    float su = e;
    #pragma unroll
    for (int off = 32; off >= 1; off >>= 1) su += __shfl_xor(su, off);
    lds_aw[t] = e / su;
  }
  __syncthreads();

  const float* fp = feat + (size_t)b * R_ * F_ + f0 + t * 2;
  float qx = 0.f, qy = 0.f;
  #pragma unroll 8
  for (int r = 0; r < R_; ++r) {
    float a = lds_aw[r];
    float2 v = *reinterpret_cast<const float2*>(fp + (size_t)r * F_);
    qx += a * v.x;
    qy += a * v.y;
  }
  *reinterpret_cast<float2*>(out + (size_t)b * F_ + f0 + t * 2) = (float2){qx, qy};
}

extern "C" void kernel_launch(void* const* d_in, const int* in_sizes, int n_in,
                              void* d_out, int out_size, void* d_ws, size_t ws_size,
                              hipStream_t stream) {
  const float* feat = (const float*)d_in[0];   // [B,R,F]
  const float* prev = (const float*)d_in[1];   // [B,H]
  const float* Ww   = (const float*)d_in[2];   // [F,DIM]
  const float* Wb   = (const float*)d_in[3];   // [DIM]
  const float* W2w  = (const float*)d_in[4];   // [H,DIM]
  const float* W2b  = (const float*)d_in[5];   // [DIM]
  const float* W3w  = (const float*)d_in[6];   // [DIM,1]
  // d_in[7] = W3_b: cancels in softmax
  float* out = (float*)d_out;

  ushort* wpack  = (ushort*)d_ws;                                          // 2 MB
  float*  pprime = (float*)((char*)d_ws + (size_t)F_ * DIM_ * 2);          // 512 KB
  float*  sp     = (float*)((char*)d_ws + (size_t)F_ * DIM_ * 2
                                        + (size_t)B_ * DIM_ * 4);          // 256 KB

  pack_w_k<<<(F_ * DIM_) / 256, 256, 0, stream>>>(Ww, wpack);
  prep_p_k<<<256, 256, 0, stream>>>(prev, W2w, W2b, Wb, pprime);
  score_k<<<B_ * 4, 256, 0, stream>>>(feat, wpack, pprime, W3w, sp);
  wsum_k<<<B_ * 4, 256, 0, stream>>>(feat, sp, out);
}

// Round 6
// 118.088 us; speedup vs baseline: 2.5578x; 2.5578x over previous
//
#include <hip/hip_runtime.h>
#include <hip/hip_bf16.h>

// attention_84464826843938: additive-attention pooling, MI355X (gfx950)
//
// R6: m97-style score GEMM — global_load_lds (async DMA) staging of raw fp32
// A-tiles, fp32->bf16 conversion AFTER ds_read (in-register, pre-MFMA).
//  - R5 postmortem: direct A-frag gather = 16 lines/instr, latency chains.
//  - R2/R4 postmortem: reg-staging (load->cvt->ds_write) chains VGPR deps into
//    the pre-barrier vmcnt(0) drain; gload_lds DMA is fire-and-forget and has
//    a full K-step to land before its drain (m97 pattern).
//  - LDS source-swizzle (chunk ^= row&15) on the GLOBAL address keeps the DMA
//    dest linear (HW requirement) while de-conflicting the ds_read side.
//  score_k: grid = 2 slices x 256 b (slice-major, XCD-local), 512 thr/8 waves,
//           wave = 64 rows x 32 cols, BK=64, 1 barrier/step.

#define B_ 256
#define R_ 64
#define F_ 2048
#define H_ 512
#define DIM_ 512

typedef short bf16x8 __attribute__((ext_vector_type(8)));
typedef float f32x4 __attribute__((ext_vector_type(4)));

__device__ __forceinline__ ushort f2bf(float x) {
  __hip_bfloat16 h = __float2bfloat16(x);
  return __builtin_bit_cast(ushort, h);
}

__device__ __forceinline__ uint4 pack8(float4 x, float4 y) {
  uint4 r;
  r.x = (uint)f2bf(x.x) | ((uint)f2bf(x.y) << 16);
  r.y = (uint)f2bf(x.z) | ((uint)f2bf(x.w) << 16);
  r.z = (uint)f2bf(y.x) | ((uint)f2bf(y.y) << 16);
  r.w = (uint)f2bf(y.z) | ((uint)f2bf(y.w) << 16);
  return r;
}

__device__ __forceinline__ void gld16(const float* g, float* l) {
  __builtin_amdgcn_global_load_lds(
      (const __attribute__((address_space(1))) unsigned int*)(g),
      (__attribute__((address_space(3))) unsigned int*)(l),
      16, 0, 0);
}

// wpack[((kt32*32 + ctg)*64 + g*16 + c)*8 + i] = bf16(W_w[kt32*32 + g*8 + i][ctg*16 + c])
__global__ void pack_w_k(const float* __restrict__ Ww, ushort* __restrict__ wpack) {
  int idx = blockIdx.x * 256 + threadIdx.x;
  float v = Ww[idx];
  int k = idx >> 9;
  int d = idx & 511;
  int kt = k >> 5, kr = k & 31;
  int g = kr >> 3, i = kr & 7;
  int ctg = d >> 4, c = d & 15;
  size_t dst = ((size_t)((kt * 32 + ctg) * 64 + g * 16 + c)) * 8 + (size_t)i;
  wpack[dst] = f2bf(v);
}

// p'[b][d] = prev[b]@W2_w[:,d] + W2_b[d] + W_b[d]
__global__ __launch_bounds__(256) void prep_p_k(const float* __restrict__ prev,
                                                const float* __restrict__ W2w,
                                                const float* __restrict__ W2b,
                                                const float* __restrict__ Wb,
                                                float* __restrict__ pprime) {
  __shared__ float lprev[8][H_];
  int bg = blockIdx.x >> 3;
  int d0 = (blockIdx.x & 7) * 64;
  int t = threadIdx.x;
  const float4* src = reinterpret_cast<const float4*>(prev + (size_t)bg * 8 * H_);
  float4* dst = reinterpret_cast<float4*>(&lprev[0][0]);
  for (int i = t; i < 8 * H_ / 4; i += 256) dst[i] = src[i];
  __syncthreads();
  int d = d0 + (t & 63);
  int bq = t >> 6;
  float a0 = 0.f, a1 = 0.f;
  #pragma unroll 8
  for (int h = 0; h < H_; ++h) {
    float wv = W2w[h * DIM_ + d];
    a0 += lprev[bq][h] * wv;
    a1 += lprev[bq + 4][h] * wv;
  }
  float bias = W2b[d] + Wb[d];
  pprime[(size_t)(bg * 8 + bq) * DIM_ + d] = a0 + bias;
  pprime[(size_t)(bg * 8 + bq + 4) * DIM_ + d] = a1 + bias;
}

__device__ __forceinline__ float fast_tanh(float x) {
  float e = __expf(2.f * x);
  return 1.f - 2.f / (e + 1.f);
}

// sp[b*2+slice][r] = sum_{d in slice's 256 cols} tanh(c[b][r][d]+p'[b][d])*W3[d]
__global__ __launch_bounds__(512, 4) void score_k(const float* __restrict__ feat,
                                                  const ushort* __restrict__ wpack,
                                                  const float* __restrict__ pprime,
                                                  const float* __restrict__ W3,
                                                  float* __restrict__ sp) {
  int slice = blockIdx.x >> 8;          // slice-major: both slices of b same XCD
  int b = blockIdx.x & 255;
  int t = threadIdx.x;
  int wid = t >> 6;                     // 8 waves; wave owns cols [wid*32,+32)
  int l = t & 63;
  int l15 = l & 15, g = l >> 4;
  const float* featB = feat + (size_t)b * R_ * F_;

  // A tile [64 rows][64 k] fp32, source-swizzled: content(row, cq) =
  //   feat[row][kt*64 + (cq ^ (row&15))*4 .. +4]   (cq = 16B chunk, 16/row)
  __shared__ float ldsA[2][4096];       // 2 x 16 KB double buffer
  __shared__ float lds_part[8][R_];

  f32x4 acc[4][2];
  #pragma unroll
  for (int rt = 0; rt < 4; ++rt)
    #pragma unroll
    for (int ct = 0; ct < 2; ++ct)
      acc[rt][ct] = (f32x4){0.f, 0.f, 0.f, 0.f};

  // ---- staging geometry (DMA): wave wid writes LDS bytes [wid*1024,+1024)
  // (rows wid*4..wid*4+3) and the mirror +8192 (rows +32). Lane (l15,g):
  // slot row = wid*4+g, chunk-in-LDS = l15, global chunk = l15 ^ (row&15).
  int srow = wid * 4 + g;               // 0..31
  int schunk = l15 ^ (srow & 15);
  const float* sg0 = featB + (size_t)srow * F_ + schunk * 4;
  const float* sg1 = sg0 + (size_t)32 * F_;
  float* lbA0 = &ldsA[0][wid * 256];    // wave-uniform bases
  float* lbA1 = lbA0 + 2048;
  float* lbB0 = &ldsA[1][wid * 256];
  float* lbB1 = lbB0 + 2048;

  // ---- A-frag read offsets (float units): row = rt*16+l15, chunk = s*8+g*2+h,
  // swizzled chunk' = chunk ^ l15 (row&15 == l15 on read side).
  int aoff[2][2];
  #pragma unroll
  for (int s = 0; s < 2; ++s)
    #pragma unroll
    for (int h = 0; h < 2; ++h)
      aoff[s][h] = l15 * 64 + (((s * 8 + g * 2 + h) ^ l15) * 4);

  // ---- B pointer: frag(kt,s,ct) at wp + kt*32768 + s*16384 + ct*512 (ushorts)
  const ushort* wp = wpack + (size_t)(slice * 16 + wid * 2) * 512 + (size_t)l * 8;

  // prologue: DMA tile 0 into buf0; B(0) into regs
  gld16(sg0, lbA0);
  gld16(sg1, lbA1);
  uint4 bc[2][2];
  #pragma unroll
  for (int s = 0; s < 2; ++s)
    #pragma unroll
    for (int ct = 0; ct < 2; ++ct)
      bc[s][ct] = *reinterpret_cast<const uint4*>(wp + s * 16384 + ct * 512);

  for (int kt = 0; kt < 32; ++kt) {
    int cur = kt & 1;
    __syncthreads();                    // drains DMA(kt) + B(kt) (issued a full step ago)

    // issue DMA(kt+1) into the other buffer (fire-and-forget)
    if (kt < 31) {
      const float* gn0 = sg0 + (size_t)(kt + 1) * 64;
      const float* gn1 = sg1 + (size_t)(kt + 1) * 64;
      if (cur == 0) { gld16(gn0, lbB0); gld16(gn1, lbB1); }
      else          { gld16(gn0, lbA0); gld16(gn1, lbA1); }
    }
    // issue B(kt+1) into regs
    uint4 bn[2][2];
    if (kt < 31) {
      const ushort* wpn = wp + (size_t)(kt + 1) * 32768;
      #pragma unroll
      for (int s = 0; s < 2; ++s)
        #pragma unroll
        for (int ct = 0; ct < 2; ++ct)
          bn[s][ct] = *reinterpret_cast<const uint4*>(wpn + s * 16384 + ct * 512);
    }

    // compute on buf[cur]: ds_read fp32 frags -> cvt bf16 -> MFMA
    const float* Abuf = &ldsA[cur][0];
    #pragma unroll
    for (int s = 0; s < 2; ++s) {
      bf16x8 af[4];
      #pragma unroll
      for (int rt = 0; rt < 4; ++rt) {
        float4 x = *reinterpret_cast<const float4*>(&Abuf[rt * 1024 + aoff[s][0]]);
        float4 y = *reinterpret_cast<const float4*>(&Abuf[rt * 1024 + aoff[s][1]]);
        af[rt] = __builtin_bit_cast(bf16x8, pack8(x, y));
      }
      #pragma unroll
      for (int ct = 0; ct < 2; ++ct) {
        bf16x8 bv = __builtin_bit_cast(bf16x8, bc[s][ct]);
        #pragma unroll
        for (int rt = 0; rt < 4; ++rt)
          acc[rt][ct] = __builtin_amdgcn_mfma_f32_16x16x32_bf16(af[rt], bv, acc[rt][ct], 0, 0, 0);
      }
    }

    if (kt < 31) {
      #pragma unroll
      for (int s = 0; s < 2; ++s)
        #pragma unroll
        for (int ct = 0; ct < 2; ++ct)
          bc[s][ct] = bn[s][ct];
    }
  }

  // epilogue: tanh + W3 dot in registers
  // acc[rt][ct][j] = c[row = rt*16 + g*4 + j][col = slice*256 + wid*32 + ct*16 + l15]
  float pp[2], w3v[2];
  #pragma unroll
  for (int ct = 0; ct < 2; ++ct) {
    int col = slice * 256 + wid * 32 + ct * 16 + l15;
    pp[ct] = pprime[b * DIM_ + col];
    w3v[ct] = W3[col];
  }
  #pragma unroll
  for (int rt = 0; rt < 4; ++rt) {
    #pragma unroll
    for (int j = 0; j < 4; ++j) {
      float v = fast_tanh(acc[rt][0][j] + pp[0]) * w3v[0]
              + fast_tanh(acc[rt][1][j] + pp[1]) * w3v[1];
      v += __shfl_xor(v, 1);
      v += __shfl_xor(v, 2);
      v += __shfl_xor(v, 4);
      v += __shfl_xor(v, 8);
      if (l15 == 0) lds_part[wid][rt * 16 + g * 4 + j] = v;
    }
  }
  __syncthreads();

  if (t < R_) {
    float s = 0.f;
    #pragma unroll
    for (int w = 0; w < 8; ++w) s += lds_part[w][t];
    sp[((size_t)b * 2 + slice) * R_ + t] = s;
  }
}

// softmax + weighted sum: grid = B*4, 256 thr, 512 f per block
__global__ __launch_bounds__(256) void wsum_k(const float* __restrict__ feat,
                                              const float* __restrict__ sp,
                                              float* __restrict__ out) {
  int b = blockIdx.x >> 2;
  int f0 = (blockIdx.x & 3) * 512;
  int t = threadIdx.x;
  __shared__ float lds_aw[R_];

  if (t < R_) {
    float s = sp[((size_t)b * 2 + 0) * R_ + t] + sp[((size_t)b * 2 + 1) * R_ + t];
    float m = s;
    #pragma unroll
    for (int off = 32; off >= 1; off >>= 1) m = fmaxf(m, __shfl_xor(m, off));
    float e = __expf(s - m);
    float su = e;
    #pragma unroll
    for (int off = 32; off >= 1; off >>= 1) su += __shfl_xor(su, off);
    lds_aw[t] = e / su;
  }
  __syncthreads();

  const float* fp = feat + (size_t)b * R_ * F_ + f0 + t * 2;
  float qx = 0.f, qy = 0.f;
  #pragma unroll 8
  for (int r = 0; r < R_; ++r) {
    float a = lds_aw[r];
    float2 v = *reinterpret_cast<const float2*>(fp + (size_t)r * F_);
    qx += a * v.x;
    qy += a * v.y;
  }
  *reinterpret_cast<float2*>(out + (size_t)b * F_ + f0 + t * 2) = (float2){qx, qy};
}

extern "C" void kernel_launch(void* const* d_in, const int* in_sizes, int n_in,
                              void* d_out, int out_size, void* d_ws, size_t ws_size,
                              hipStream_t stream) {
  const float* feat = (const float*)d_in[0];   // [B,R,F]
  const float* prev = (const float*)d_in[1];   // [B,H]
  const float* Ww   = (const float*)d_in[2];   // [F,DIM]
  const float* Wb   = (const float*)d_in[3];   // [DIM]
  const float* W2w  = (const float*)d_in[4];   // [H,DIM]
  const float* W2b  = (const float*)d_in[5];   // [DIM]
  const float* W3w  = (const float*)d_in[6];   // [DIM,1]
  // d_in[7] = W3_b: cancels in softmax
  float* out = (float*)d_out;

  ushort* wpack  = (ushort*)d_ws;                                          // 2 MB
  float*  pprime = (float*)((char*)d_ws + (size_t)F_ * DIM_ * 2);          // 512 KB
  float*  sp     = (float*)((char*)d_ws + (size_t)F_ * DIM_ * 2
                                        + (size_t)B_ * DIM_ * 4);          // 128 KB

  pack_w_k<<<(F_ * DIM_) / 256, 256, 0, stream>>>(Ww, wpack);
  prep_p_k<<<256, 256, 0, stream>>>(prev, W2w, W2b, Wb, pprime);
  score_k<<<B_ * 2, 512, 0, stream>>>(feat, wpack, pprime, W3w, sp);
  wsum_k<<<B_ * 4, 256, 0, stream>>>(feat, sp, out);
}

// Round 7
// 103.389 us; speedup vs baseline: 2.9215x; 1.1422x over previous
//
#include <hip/hip_runtime.h>
#include <hip/hip_bf16.h>

// attention_84464826843938: additive-attention pooling, MI355X (gfx950)
//
// R7: counted-vmcnt pipeline (T3/T4) + shared cvt.
//  R6 postmortem: (1) each of 8 waves converted the WHOLE A-tile fp32->bf16
//  every step (8x redundant VALU = 39% VALUBusy); (2) __syncthreads emits
//  s_waitcnt vmcnt(0) -> drains the just-issued DMA every region, capping
//  pipeline depth at ~1 region (~400cyc) vs ~900cyc HBM latency.
//  Fix: raw s_barrier + counted vmcnt (derived N=10/8), lgkmcnt(0) for
//  ds_write visibility, memory-clobber asm fences both sides of the barrier.
//  A-path: DMA raw fp32 tile (3-deep ring, source-XOR-swizzle) -> one shared
//  cvt phase (512 thr) -> bf16 frag tile (2-deep, XOR-swizzle) -> ds_read_b128.
//  score_k: grid = 2 slices x 256 b (slice-major, XCD-local), 512 thr/8 waves,
//  wave = 64 rows x 32 cols, BK=64, one barrier/region.

#define B_ 256
#define R_ 64
#define F_ 2048
#define H_ 512
#define DIM_ 512

typedef short bf16x8 __attribute__((ext_vector_type(8)));
typedef float f32x4 __attribute__((ext_vector_type(4)));

__device__ __forceinline__ ushort f2bf(float x) {
  __hip_bfloat16 h = __float2bfloat16(x);
  return __builtin_bit_cast(ushort, h);
}

__device__ __forceinline__ uint4 pack8(float4 x, float4 y) {
  uint4 r;
  r.x = (uint)f2bf(x.x) | ((uint)f2bf(x.y) << 16);
  r.y = (uint)f2bf(x.z) | ((uint)f2bf(x.w) << 16);
  r.z = (uint)f2bf(y.x) | ((uint)f2bf(y.y) << 16);
  r.w = (uint)f2bf(y.z) | ((uint)f2bf(y.w) << 16);
  return r;
}

__device__ __forceinline__ void gld16(const float* g, float* l) {
  __builtin_amdgcn_global_load_lds(
      (const __attribute__((address_space(1))) unsigned int*)(g),
      (__attribute__((address_space(3))) unsigned int*)(l),
      16, 0, 0);
}

// wpack[((kt32*32 + ctg)*64 + g*16 + c)*8 + i] = bf16(W_w[kt32*32 + g*8 + i][ctg*16 + c])
__global__ void pack_w_k(const float* __restrict__ Ww, ushort* __restrict__ wpack) {
  int idx = blockIdx.x * 256 + threadIdx.x;
  float v = Ww[idx];
  int k = idx >> 9;
  int d = idx & 511;
  int kt = k >> 5, kr = k & 31;
  int g = kr >> 3, i = kr & 7;
  int ctg = d >> 4, c = d & 15;
  size_t dst = ((size_t)((kt * 32 + ctg) * 64 + g * 16 + c)) * 8 + (size_t)i;
  wpack[dst] = f2bf(v);
}

// p'[b][d] = prev[b]@W2_w[:,d] + W2_b[d] + W_b[d]
__global__ __launch_bounds__(256) void prep_p_k(const float* __restrict__ prev,
                                                const float* __restrict__ W2w,
                                                const float* __restrict__ W2b,
                                                const float* __restrict__ Wb,
                                                float* __restrict__ pprime) {
  __shared__ float lprev[8][H_];
  int bg = blockIdx.x >> 3;
  int d0 = (blockIdx.x & 7) * 64;
  int t = threadIdx.x;
  const float4* src = reinterpret_cast<const float4*>(prev + (size_t)bg * 8 * H_);
  float4* dst = reinterpret_cast<float4*>(&lprev[0][0]);
  for (int i = t; i < 8 * H_ / 4; i += 256) dst[i] = src[i];
  __syncthreads();
  int d = d0 + (t & 63);
  int bq = t >> 6;
  float a0 = 0.f, a1 = 0.f;
  #pragma unroll 8
  for (int h = 0; h < H_; ++h) {
    float wv = W2w[h * DIM_ + d];
    a0 += lprev[bq][h] * wv;
    a1 += lprev[bq + 4][h] * wv;
  }
  float bias = W2b[d] + Wb[d];
  pprime[(size_t)(bg * 8 + bq) * DIM_ + d] = a0 + bias;
  pprime[(size_t)(bg * 8 + bq + 4) * DIM_ + d] = a1 + bias;
}

__device__ __forceinline__ float fast_tanh(float x) {
  float e = __expf(2.f * x);
  return 1.f - 2.f / (e + 1.f);
}

// sp[b*2+slice][r] = sum_{d in slice's 256 cols} tanh(c[b][r][d]+p'[b][d])*W3[d]
__global__ __launch_bounds__(512, 4) void score_k(const float* __restrict__ feat,
                                                  const ushort* __restrict__ wpack,
                                                  const float* __restrict__ pprime,
                                                  const float* __restrict__ W3,
                                                  float* __restrict__ sp) {
  int slice = blockIdx.x >> 8;          // slice-major: both slices of b same XCD
  int b = blockIdx.x & 255;
  int t = threadIdx.x;
  int wid = t >> 6;                     // 8 waves; wave owns cols [wid*32,+32)
  int l = t & 63;
  int l15 = l & 15, g = l >> 4;
  const float* featB = feat + (size_t)b * R_ * F_;

  // raw[buf][row][c16]: holds global 16B-chunk (c16 ^ (row&15))  [src-swizzle]
  __shared__ float raw[3][4096];        // 3 x 16 KB DMA ring
  // frg[buf][kc*64 + (row ^ ((kc*2)&15))] = bf16 A[row][k=kc*8..+8]
  __shared__ uint4 frg[2][512];         // 2 x 8 KB
  __shared__ float lds_part[8][R_];

  f32x4 acc[4][2];
  #pragma unroll
  for (int rt = 0; rt < 4; ++rt)
    #pragma unroll
    for (int ct = 0; ct < 2; ++ct)
      acc[rt][ct] = (f32x4){0.f, 0.f, 0.f, 0.f};

  // ---- DMA geometry: wave wid covers rows [wid*4, wid*4+4) and +32.
  // lane l -> LDS float offset base + l*4 => row = base_row + (l>>4), chunk (l&15).
  int srow = wid * 4 + g;
  int sch = l15 ^ (srow & 15);          // (srow+32)&15 == srow&15
  const float* sg0 = featB + (size_t)srow * F_ + sch * 4;
  const float* sg1 = featB + (size_t)(srow + 32) * F_ + sch * 4;

  // ---- cvt geometry: thread t handles row = t>>3, k-chunk pair cj2 = (t&7)*2
  int crow = t >> 3, cj2 = (t & 7) * 2;
  int rm = crow & 15;
  int cw = (t & 7) * 64 + (crow ^ (cj2 & 15));   // frag store index

  // ---- B pointer: frag(kt,s,ct) at wp + kt*32768 + s*16384 + ct*512 (ushorts)
  const ushort* wp = wpack + (size_t)(slice * 16 + wid * 2) * 512 + (size_t)l * 8;

#define STAGE(buf, kt) do {                                        \
    gld16(sg0 + (size_t)(kt) * 64, &raw[buf][wid * 256]);          \
    gld16(sg1 + (size_t)(kt) * 64, &raw[buf][2048 + wid * 256]);   \
  } while (0)

#define LOADB(dst, kt) do {                                        \
    const ushort* wpk_ = wp + (size_t)(kt) * 32768;                \
    dst[0][0] = *reinterpret_cast<const uint4*>(wpk_);             \
    dst[0][1] = *reinterpret_cast<const uint4*>(wpk_ + 512);       \
    dst[1][0] = *reinterpret_cast<const uint4*>(wpk_ + 16384);     \
    dst[1][1] = *reinterpret_cast<const uint4*>(wpk_ + 16384 + 512); \
  } while (0)

#define CVT(nb, fb) do {                                           \
    const float* rb_ = &raw[nb][crow * 64];                        \
    float4 x_ = *reinterpret_cast<const float4*>(rb_ + ((cj2 + 0) ^ rm) * 4); \
    float4 y_ = *reinterpret_cast<const float4*>(rb_ + ((cj2 + 1) ^ rm) * 4); \
    frg[fb][cw] = pack8(x_, y_);                                   \
  } while (0)

#define MFMA_STEP(fb) do {                                         \
    _Pragma("unroll")                                              \
    for (int s_ = 0; s_ < 2; ++s_) {                               \
      bf16x8 af_[4];                                               \
      int kc_ = s_ * 4 + g;                                        \
      _Pragma("unroll")                                            \
      for (int rt_ = 0; rt_ < 4; ++rt_)                            \
        af_[rt_] = __builtin_bit_cast(bf16x8,                      \
            frg[fb][kc_ * 64 + ((rt_ * 16 + l15) ^ ((kc_ * 2) & 15))]); \
      _Pragma("unroll")                                            \
      for (int ct_ = 0; ct_ < 2; ++ct_) {                          \
        bf16x8 bv_ = __builtin_bit_cast(bf16x8, bc[s_][ct_]);      \
        _Pragma("unroll")                                          \
        for (int rt_ = 0; rt_ < 4; ++rt_)                          \
          acc[rt_][ct_] = __builtin_amdgcn_mfma_f32_16x16x32_bf16( \
              af_[rt_], bv_, acc[rt_][ct_], 0, 0, 0);              \
      }                                                            \
    }                                                              \
  } while (0)

  uint4 bc[2][2];
  // prologue: D0, D1 in flight; B0 in flight
  STAGE(0, 0);
  STAGE(1, 1);
  LOADB(bc, 0);
  // need D0 (oldest 2 of {D0,D1,B0}=8)
  asm volatile("s_waitcnt vmcnt(6)" ::: "memory");
  __builtin_amdgcn_s_barrier();
  asm volatile("" ::: "memory");
  STAGE(2, 2);                          // post-barrier: raw2 untouched, safe
  CVT(0, 0);                            // tile 0 -> frag 0

  int cur3 = 0;                         // kt % 3
  for (int kt = 0; kt < 32; ++kt) {
    uint4 bn[2][2];
    if (kt < 31) LOADB(bn, kt + 1);
    // steady: outstanding = D(kt+1)[2], B(kt)[4], D(kt+2)[2], B(kt+1)[4] = 12;
    // need D(kt+1) (for cvt(kt+1)) -> keep newest 10. Tail: kt=30 -> 8.
    if (kt < 30) {
      asm volatile("s_waitcnt vmcnt(10) lgkmcnt(0)" ::: "memory");
    } else if (kt == 30) {
      asm volatile("s_waitcnt vmcnt(8) lgkmcnt(0)" ::: "memory");
    } else {
      asm volatile("s_waitcnt lgkmcnt(0)" ::: "memory");
    }
    __builtin_amdgcn_s_barrier();
    asm volatile("" ::: "memory");

    if (kt < 29) STAGE(cur3, kt + 3);   // raw[(kt+3)%3] == raw[kt%3]; its tile-kt
                                        // reads finished last region (lgkm+barrier)
    int nxt3 = (cur3 == 2) ? 0 : cur3 + 1;
    if (kt < 31) CVT(nxt3, (kt + 1) & 1);
    MFMA_STEP(kt & 1);
    if (kt < 31) {
      #pragma unroll
      for (int s_ = 0; s_ < 2; ++s_)
        #pragma unroll
        for (int ct_ = 0; ct_ < 2; ++ct_)
          bc[s_][ct_] = bn[s_][ct_];
    }
    cur3 = nxt3;
  }

#undef STAGE
#undef LOADB
#undef CVT
#undef MFMA_STEP

  // epilogue: tanh + W3 dot in registers
  // acc[rt][ct][j] = c[row = rt*16 + g*4 + j][col = slice*256 + wid*32 + ct*16 + l15]
  float pp[2], w3v[2];
  #pragma unroll
  for (int ct = 0; ct < 2; ++ct) {
    int col = slice * 256 + wid * 32 + ct * 16 + l15;
    pp[ct] = pprime[b * DIM_ + col];
    w3v[ct] = W3[col];
  }
  #pragma unroll
  for (int rt = 0; rt < 4; ++rt) {
    #pragma unroll
    for (int j = 0; j < 4; ++j) {
      float v = fast_tanh(acc[rt][0][j] + pp[0]) * w3v[0]
              + fast_tanh(acc[rt][1][j] + pp[1]) * w3v[1];
      v += __shfl_xor(v, 1);
      v += __shfl_xor(v, 2);
      v += __shfl_xor(v, 4);
      v += __shfl_xor(v, 8);
      if (l15 == 0) lds_part[wid][rt * 16 + g * 4 + j] = v;
    }
  }
  __syncthreads();

  if (t < R_) {
    float s = 0.f;
    #pragma unroll
    for (int w = 0; w < 8; ++w) s += lds_part[w][t];
    sp[((size_t)b * 2 + slice) * R_ + t] = s;
  }
}

// softmax + weighted sum: grid = B*4, 256 thr, 512 f per block
__global__ __launch_bounds__(256) void wsum_k(const float* __restrict__ feat,
                                              const float* __restrict__ sp,
                                              float* __restrict__ out) {
  int b = blockIdx.x >> 2;
  int f0 = (blockIdx.x & 3) * 512;
  int t = threadIdx.x;
  __shared__ float lds_aw[R_];

  if (t < R_) {
    float s = sp[((size_t)b * 2 + 0) * R_ + t] + sp[((size_t)b * 2 + 1) * R_ + t];
    float m = s;
    #pragma unroll
    for (int off = 32; off >= 1; off >>= 1) m = fmaxf(m, __shfl_xor(m, off));
    float e = __expf(s - m);
    float su = e;
    #pragma unroll
    for (int off = 32; off >= 1; off >>= 1) su += __shfl_xor(su, off);
    lds_aw[t] = e / su;
  }
  __syncthreads();

  const float* fp = feat + (size_t)b * R_ * F_ + f0 + t * 2;
  float qx = 0.f, qy = 0.f;
  #pragma unroll 8
  for (int r = 0; r < R_; ++r) {
    float a = lds_aw[r];
    float2 v = *reinterpret_cast<const float2*>(fp + (size_t)r * F_);
    qx += a * v.x;
    qy += a * v.y;
  }
  *reinterpret_cast<float2*>(out + (size_t)b * F_ + f0 + t * 2) = (float2){qx, qy};
}

extern "C" void kernel_launch(void* const* d_in, const int* in_sizes, int n_in,
                              void* d_out, int out_size, void* d_ws, size_t ws_size,
                              hipStream_t stream) {
  const float* feat = (const float*)d_in[0];   // [B,R,F]
  const float* prev = (const float*)d_in[1];   // [B,H]
  const float* Ww   = (const float*)d_in[2];   // [F,DIM]
  const float* Wb   = (const float*)d_in[3];   // [DIM]
  const float* W2w  = (const float*)d_in[4];   // [H,DIM]
  const float* W2b  = (const float*)d_in[5];   // [DIM]
  const float* W3w  = (const float*)d_in[6];   // [DIM,1]
  // d_in[7] = W3_b: cancels in softmax
  float* out = (float*)d_out;

  ushort* wpack  = (ushort*)d_ws;                                          // 2 MB
  float*  pprime = (float*)((char*)d_ws + (size_t)F_ * DIM_ * 2);          // 512 KB
  float*  sp     = (float*)((char*)d_ws + (size_t)F_ * DIM_ * 2
                                        + (size_t)B_ * DIM_ * 4);          // 128 KB

  pack_w_k<<<(F_ * DIM_) / 256, 256, 0, stream>>>(Ww, wpack);
  prep_p_k<<<256, 256, 0, stream>>>(prev, W2w, W2b, Wb, pprime);
  score_k<<<B_ * 2, 512, 0, stream>>>(feat, wpack, pprime, W3w, sp);
  wsum_k<<<B_ * 4, 256, 0, stream>>>(feat, sp, out);
}